// Round 14
// baseline (63.829 us; speedup 1.0000x reference)
//
#include <hip/hip_runtime.h>
#include <hip/hip_bf16.h>

// Problem constants
#define B 64
#define S 512
#define D 768
#define K 8
#define R 277
#define NSPAN 10     // h, t, 8 bridge spans per batch
#define M_TOT 640    // pooled rows: [u: 0..63][v: 64..127][bi: 128..639]
#define DD (D*D)

typedef unsigned short ushort_t;
typedef __attribute__((ext_vector_type(8))) short short8;
typedef __attribute__((ext_vector_type(4))) float f32x4;

__device__ __forceinline__ ushort_t f2bf(float f) {
    unsigned u = __float_as_uint(f);
    unsigned r = (u + 0x7FFFu + ((u >> 16) & 1u)) >> 16;   // RNE
    return (ushort_t)r;
}

// ---------------------------------------------------------------------------
// Pool phase 1 + weight cvt. Grid (B, NCH+CVTY), 192 thr.
//  y < NCH : PURE per-chunk max over RPC=8 rows (no span logic; max is
//            idempotent so span assembly happens in pool2). Streaming.
//  y >= NCH: fp32->bf16 conversion of {wu,wv,wi,ln1_w,pred_w} (independent)
// ---------------------------------------------------------------------------
template<int RPC, int NCH, int CVTY>
__global__ void k_pool1(const float* __restrict__ emb,
                        const float* __restrict__ wu,
                        const float* __restrict__ wv,
                        const float* __restrict__ wi,
                        const float* __restrict__ ln1_w,
                        const float* __restrict__ pred_w,
                        float* __restrict__ chunkmax,
                        ushort_t* __restrict__ wbf) {
    int b = blockIdx.x, c = blockIdx.y;
    int t = threadIdx.x;

    if (c >= NCH) {
        // ---- cvt role: 8 elems/thread over 4*D*D + R*D elements ----
        int g = (b * CVTY + (c - NCH)) * 192 + t;
        size_t e0 = (size_t)g * 8;
        const size_t TOT = (size_t)4*DD + (size_t)R*D;
        if (e0 < TOT) {
            const float* src; size_t off;
            if      (e0 < (size_t)DD)   { src = wu;     off = e0; }
            else if (e0 < (size_t)2*DD) { src = wv;     off = e0 - DD; }
            else if (e0 < (size_t)3*DD) { src = wi;     off = e0 - (size_t)2*DD; }
            else if (e0 < (size_t)4*DD) { src = ln1_w;  off = e0 - (size_t)3*DD; }
            else                        { src = pred_w; off = e0 - (size_t)4*DD; }
            float4 f0 = *(const float4*)(src + off);
            float4 f1 = *(const float4*)(src + off + 4);
            short8 o;
            o[0] = (short)f2bf(f0.x); o[1] = (short)f2bf(f0.y);
            o[2] = (short)f2bf(f0.z); o[3] = (short)f2bf(f0.w);
            o[4] = (short)f2bf(f1.x); o[5] = (short)f2bf(f1.y);
            o[6] = (short)f2bf(f1.z); o[7] = (short)f2bf(f1.w);
            *(short8*)&wbf[e0] = o;
        }
        return;
    }

    // ---- chunk-max role: max over rows [c*RPC, c*RPC+RPC) ----
    const float4* e4 = (const float4*)(emb + (size_t)b * S * D)
                     + (size_t)(c * RPC) * (D/4) + t;
    float4 m = make_float4(-INFINITY, -INFINITY, -INFINITY, -INFINITY);
    #pragma unroll
    for (int i = 0; i < RPC; ++i) {
        float4 v = e4[i * (D/4)];
        m.x = fmaxf(m.x, v.x); m.y = fmaxf(m.y, v.y);
        m.z = fmaxf(m.z, v.z); m.w = fmaxf(m.w, v.w);
    }
    *(float4*)(chunkmax + ((size_t)b * NCH + c) * D + t*4) = m;
}

// ---------------------------------------------------------------------------
// Pool phase 2: per (b, span j): combine full-chunk maxes + boundary rows
// (direct from emb, L3-warm). Head/tail ranges may double-count rows —
// harmless for max. Writes pooled as BF16.
// ---------------------------------------------------------------------------
template<int RPC, int NCH>
__global__ void k_pool2(const float* __restrict__ chunkmax,
                        const float* __restrict__ emb,
                        const int* __restrict__ h_span,
                        const int* __restrict__ t_span,
                        const int* __restrict__ b_spans,
                        ushort_t* __restrict__ pooled_bf) {
    int task = blockIdx.x;
    int b = task / NSPAN, j = task % NSPAN;
    int s0, s1, row;
    if (j == 0)      { s0 = h_span[b*2]; s1 = h_span[b*2+1]; row = b; }
    else if (j == 1) { s0 = t_span[b*2]; s1 = t_span[b*2+1]; row = B + b; }
    else {
        int k = j - 2;
        s0 = b_spans[(b*K+k)*2]; s1 = b_spans[(b*K+k)*2 + 1];
        row = 2*B + b*K + k;
    }
    int t = threadIdx.x;

    int c_lo = (s0 + RPC - 1) / RPC;        // first fully-covered chunk
    int c_hi = (s1 + 1) / RPC - 1;          // last fully-covered chunk

    float4 m = make_float4(-INFINITY, -INFINITY, -INFINITY, -INFINITY);
    const float4* cm = (const float4*)(chunkmax + (size_t)b * NCH * D) + t;
    for (int c = c_lo; c <= c_hi; ++c) {
        float4 v = cm[(size_t)c * (D/4)];
        m.x = fmaxf(m.x, v.x); m.y = fmaxf(m.y, v.y);
        m.z = fmaxf(m.z, v.z); m.w = fmaxf(m.w, v.w);
    }
    const float4* e4 = (const float4*)(emb + (size_t)b * S * D) + t;
    int h_end = min(s1, c_lo * RPC - 1);
    for (int s = s0; s <= h_end; ++s) {
        float4 v = e4[(size_t)s * (D/4)];
        m.x = fmaxf(m.x, v.x); m.y = fmaxf(m.y, v.y);
        m.z = fmaxf(m.z, v.z); m.w = fmaxf(m.w, v.w);
    }
    int t_beg = max(s0, (c_hi + 1) * RPC);
    for (int s = t_beg; s <= s1; ++s) {
        float4 v = e4[(size_t)s * (D/4)];
        m.x = fmaxf(m.x, v.x); m.y = fmaxf(m.y, v.y);
        m.z = fmaxf(m.z, v.z); m.w = fmaxf(m.w, v.w);
    }

    unsigned lo = (unsigned)f2bf(m.x) | ((unsigned)f2bf(m.y) << 16);
    unsigned hi = (unsigned)f2bf(m.z) | ((unsigned)f2bf(m.w) << 16);
    *(uint2*)&pooled_bf[(size_t)row * D + t*4] = make_uint2(lo, hi);
}

// ---------------------------------------------------------------------------
// Projection GEMM via bf16 MFMA 16x16x32 (R9-verified). grid (12,10,KSPLIT=2).
// ---------------------------------------------------------------------------
template<int KSPLIT>
__global__ __launch_bounds__(256)
void k_gemm_bf(const ushort_t* __restrict__ abf,
               const ushort_t* __restrict__ wbf,
               float* __restrict__ p_part) {
    __shared__ ushort_t Al[64][64];
    __shared__ ushort_t Bl[64][64];
    int e0 = blockIdx.x * 64;
    int m0 = blockIdx.y * 64;
    int dbase = blockIdx.z * (D / KSPLIT);
    const ushort_t* Wm = wbf + (size_t)((m0 < B) ? 0 : (m0 < 2*B) ? 1 : 2) * DD;

    int tid = threadIdx.x;
    int w = tid >> 6, l = tid & 63;
    int srow = tid >> 2;
    int sc   = tid & 3;

    const ushort_t* ga = abf + (size_t)(m0 + srow) * D + dbase;
    const ushort_t* gb = Wm  + (size_t)(e0 + srow) * D + dbase;
    int p0 = ((sc     ) ^ (srow & 7)) * 8;
    int p1 = ((sc + 4 ) ^ (srow & 7)) * 8;

    f32x4 acc[4] = {};
    const int NIT = (D / KSPLIT) / 64;
    short8 pa0 = *(const short8*)(ga + sc*8);
    short8 pa1 = *(const short8*)(ga + sc*8 + 32);
    short8 pb0 = *(const short8*)(gb + sc*8);
    short8 pb1 = *(const short8*)(gb + sc*8 + 32);

    for (int it = 0; it < NIT; ++it) {
        __syncthreads();
        *(short8*)&Al[srow][p0] = pa0;
        *(short8*)&Al[srow][p1] = pa1;
        *(short8*)&Bl[srow][p0] = pb0;
        *(short8*)&Bl[srow][p1] = pb1;
        __syncthreads();
        if (it + 1 < NIT) {
            ga += 64; gb += 64;
            pa0 = *(const short8*)(ga + sc*8);
            pa1 = *(const short8*)(ga + sc*8 + 32);
            pb0 = *(const short8*)(gb + sc*8);
            pb1 = *(const short8*)(gb + sc*8 + 32);
        }
        int g = l >> 4, x = l & 7;
        #pragma unroll
        for (int ks = 0; ks < 2; ++ks) {
            int chunk = ks*4 + g;
            short8 a = *(const short8*)&Al[w*16 + (l & 15)][(chunk ^ x) * 8];
            #pragma unroll
            for (int nt = 0; nt < 4; ++nt) {
                short8 bf = *(const short8*)&Bl[nt*16 + (l & 15)][(chunk ^ x) * 8];
                acc[nt] = __builtin_amdgcn_mfma_f32_16x16x32_bf16(a, bf, acc[nt], 0, 0, 0);
            }
        }
    }

    int r4 = (l >> 4) * 4, cc = l & 15;
    #pragma unroll
    for (int nt = 0; nt < 4; ++nt)
        #pragma unroll
        for (int r = 0; r < 4; ++r)
            p_part[((size_t)blockIdx.z * M_TOT + m0 + w*16 + r4 + r) * D + e0 + nt*16 + cc] = acc[nt][r];
}

// ---------------------------------------------------------------------------
// Attention: reduce partials+bias -> U,V,BI; dots; softmax; s -> BF16.
// Also initializes out[b][:] = pred_b.
// ---------------------------------------------------------------------------
template<int KSPLIT>
__global__ __launch_bounds__(512)
void k_att2(const float* __restrict__ p_part,
            const float* __restrict__ wu_b,
            const float* __restrict__ wv_b,
            const float* __restrict__ wi_b,
            const float* __restrict__ pred_b,
            ushort_t* __restrict__ s_bf,
            float* __restrict__ out) {
    __shared__ float U[D], V[D], BI[K][D];
    __shared__ float dots[K];
    int b = blockIdx.x, tid = threadIdx.x;

    for (int r = tid; r < R; r += 512) out[(size_t)b * R + r] = pred_b[r];

    for (int task = tid; task < NSPAN * (D/4); task += 512) {
        int j = task / (D/4), sl = task % (D/4);
        size_t row = (j == 0) ? (size_t)b : (j == 1) ? (size_t)(B + b)
                   : (size_t)(2*B + b*K + (j - 2));
        const float* bias = (j == 0) ? wu_b : (j == 1) ? wv_b : wi_b;
        float4 acc = *(const float4*)(bias + sl*4);
        #pragma unroll
        for (int ks = 0; ks < KSPLIT; ++ks) {
            float4 p = *(const float4*)(p_part + ((size_t)ks * M_TOT + row) * D + sl*4);
            acc.x += p.x; acc.y += p.y; acc.z += p.z; acc.w += p.w;
        }
        float* dst = (j == 0) ? U : (j == 1) ? V : BI[j-2];
        *(float4*)(dst + sl*4) = acc;
    }
    __syncthreads();

    int wave = tid >> 6, lane = tid & 63;
    {
        float part = 0.f;
        #pragma unroll
        for (int i = 0; i < D/64; ++i) {
            int d = i*64 + lane;
            part += U[d] * BI[wave][d];
        }
        #pragma unroll
        for (int off = 32; off > 0; off >>= 1) part += __shfl_xor(part, off);
        if (lane == 0) dots[wave] = part * 0.125f;   // 1/sqrt(D_K=64)
    }
    __syncthreads();

    float mx = -INFINITY;
    #pragma unroll
    for (int k = 0; k < K; ++k) mx = fmaxf(mx, dots[k]);
    float ex[K], sum = 0.f;
    #pragma unroll
    for (int k = 0; k < K; ++k) { ex[k] = expf(dots[k] - mx); sum += ex[k]; }
    float inv = 1.f / sum;
    for (int d = tid; d < D; d += 512) {
        float c = 0.f;
        #pragma unroll
        for (int k = 0; k < K; ++k) c += ex[k] * BI[k][d];
        s_bf[(size_t)b * D + d] = f2bf(U[d] + V[d] + c * inv);
    }
}

// ---------------------------------------------------------------------------
// pair GEMM via MFMA: A = s_bf [64][768], B = ln1_w bf16. grid (12, KSPL=6).
// ---------------------------------------------------------------------------
template<int KSPL>
__global__ __launch_bounds__(256)
void k_pairg_bf(const ushort_t* __restrict__ s_bf,
                const ushort_t* __restrict__ ln1_bf,
                float* __restrict__ pair_part) {
    __shared__ ushort_t Al[64][64];
    __shared__ ushort_t Bl[64][64];
    int e0 = blockIdx.x * 64;
    int dbase = blockIdx.y * (D / KSPL);

    int tid = threadIdx.x;
    int w = tid >> 6, l = tid & 63;
    int srow = tid >> 2;
    int sc   = tid & 3;

    const ushort_t* ga = s_bf   + (size_t)srow * D + dbase;
    const ushort_t* gb = ln1_bf + (size_t)(e0 + srow) * D + dbase;
    int p0 = ((sc     ) ^ (srow & 7)) * 8;
    int p1 = ((sc + 4 ) ^ (srow & 7)) * 8;

    f32x4 acc[4] = {};
    const int NIT = (D / KSPL) / 64;   // 2
    short8 pa0 = *(const short8*)(ga + sc*8);
    short8 pa1 = *(const short8*)(ga + sc*8 + 32);
    short8 pb0 = *(const short8*)(gb + sc*8);
    short8 pb1 = *(const short8*)(gb + sc*8 + 32);

    for (int it = 0; it < NIT; ++it) {
        __syncthreads();
        *(short8*)&Al[srow][p0] = pa0;
        *(short8*)&Al[srow][p1] = pa1;
        *(short8*)&Bl[srow][p0] = pb0;
        *(short8*)&Bl[srow][p1] = pb1;
        __syncthreads();
        if (it + 1 < NIT) {
            ga += 64; gb += 64;
            pa0 = *(const short8*)(ga + sc*8);
            pa1 = *(const short8*)(ga + sc*8 + 32);
            pb0 = *(const short8*)(gb + sc*8);
            pb1 = *(const short8*)(gb + sc*8 + 32);
        }
        int g = l >> 4, x = l & 7;
        #pragma unroll
        for (int ks = 0; ks < 2; ++ks) {
            int chunk = ks*4 + g;
            short8 a = *(const short8*)&Al[w*16 + (l & 15)][(chunk ^ x) * 8];
            #pragma unroll
            for (int nt = 0; nt < 4; ++nt) {
                short8 bf = *(const short8*)&Bl[nt*16 + (l & 15)][(chunk ^ x) * 8];
                acc[nt] = __builtin_amdgcn_mfma_f32_16x16x32_bf16(a, bf, acc[nt], 0, 0, 0);
            }
        }
    }

    int r4 = (l >> 4) * 4, cc = l & 15;
    #pragma unroll
    for (int nt = 0; nt < 4; ++nt)
        #pragma unroll
        for (int r = 0; r < 4; ++r)
            pair_part[((size_t)blockIdx.y * B + w*16 + r4 + r) * D + e0 + nt*16 + cc] = acc[nt][r];
}

// ---------------------------------------------------------------------------
// pred GEMM via MFMA: A = relu(sum_ks pair_part + ln1_b) built inline (bf16),
// B = pred_w bf16 (row-clamped). grid (5, KSPP=12), NIT=1, atomic epilogue.
// ---------------------------------------------------------------------------
template<int KSPP, int KSPL>
__global__ __launch_bounds__(256)
void k_predg_bf(const float* __restrict__ pair_part,
                const float* __restrict__ ln1_b,
                const ushort_t* __restrict__ pred_bf,
                float* __restrict__ out) {
    __shared__ ushort_t Al[64][64];
    __shared__ ushort_t Bl[64][64];
    int r0 = blockIdx.x * 64;
    int dbase = blockIdx.y * (D / KSPP);   // 64-elem K slice

    int tid = threadIdx.x;
    int w = tid >> 6, l = tid & 63;
    int srow = tid >> 2;
    int sc   = tid & 3;
    int p0 = ((sc     ) ^ (srow & 7)) * 8;
    int p1 = ((sc + 4 ) ^ (srow & 7)) * 8;

    auto build8 = [&](int off) -> short8 {   // off: elem offset in [0,64)
        float4 a0 = *(const float4*)(ln1_b + dbase + off);
        float4 a1 = *(const float4*)(ln1_b + dbase + off + 4);
        #pragma unroll
        for (int ks = 0; ks < KSPL; ++ks) {
            const float* p = pair_part + ((size_t)ks * B + srow) * D + dbase + off;
            float4 q0 = *(const float4*)p;
            float4 q1 = *(const float4*)(p + 4);
            a0.x += q0.x; a0.y += q0.y; a0.z += q0.z; a0.w += q0.w;
            a1.x += q1.x; a1.y += q1.y; a1.z += q1.z; a1.w += q1.w;
        }
        short8 o;
        o[0] = (short)f2bf(fmaxf(a0.x, 0.f)); o[1] = (short)f2bf(fmaxf(a0.y, 0.f));
        o[2] = (short)f2bf(fmaxf(a0.z, 0.f)); o[3] = (short)f2bf(fmaxf(a0.w, 0.f));
        o[4] = (short)f2bf(fmaxf(a1.x, 0.f)); o[5] = (short)f2bf(fmaxf(a1.y, 0.f));
        o[6] = (short)f2bf(fmaxf(a1.z, 0.f)); o[7] = (short)f2bf(fmaxf(a1.w, 0.f));
        return o;
    };

    short8 a0 = build8(sc*8);
    short8 a1 = build8(sc*8 + 32);
    int rw = r0 + srow; if (rw >= R) rw = R - 1;   // clamp (products discarded)
    const ushort_t* gb = pred_bf + (size_t)rw * D + dbase;
    short8 pb0 = *(const short8*)(gb + sc*8);
    short8 pb1 = *(const short8*)(gb + sc*8 + 32);

    *(short8*)&Al[srow][p0] = a0;
    *(short8*)&Al[srow][p1] = a1;
    *(short8*)&Bl[srow][p0] = pb0;
    *(short8*)&Bl[srow][p1] = pb1;
    __syncthreads();

    f32x4 acc[4] = {};
    int g = l >> 4, x = l & 7;
    #pragma unroll
    for (int ks = 0; ks < 2; ++ks) {
        int chunk = ks*4 + g;
        short8 a = *(const short8*)&Al[w*16 + (l & 15)][(chunk ^ x) * 8];
        #pragma unroll
        for (int nt = 0; nt < 4; ++nt) {
            short8 bf = *(const short8*)&Bl[nt*16 + (l & 15)][(chunk ^ x) * 8];
            acc[nt] = __builtin_amdgcn_mfma_f32_16x16x32_bf16(a, bf, acc[nt], 0, 0, 0);
        }
    }

    int r4 = (l >> 4) * 4, cc = l & 15;
    #pragma unroll
    for (int nt = 0; nt < 4; ++nt) {
        int rr = r0 + nt*16 + cc;
        if (rr < R) {
            #pragma unroll
            for (int r = 0; r < 4; ++r)
                atomicAdd(&out[(size_t)(w*16 + r4 + r) * R + rr], acc[nt][r]);
        }
    }
}

// ---------------------------------------------------------------------------
extern "C" void kernel_launch(void* const* d_in, const int* in_sizes, int n_in,
                              void* d_out, int out_size, void* d_ws, size_t ws_size,
                              hipStream_t stream) {
    const float* emb     = (const float*)d_in[0];
    const int*   h_span  = (const int*)  d_in[1];
    const int*   t_span  = (const int*)  d_in[2];
    const int*   b_spans = (const int*)  d_in[3];
    const float* wu_w    = (const float*)d_in[4];
    const float* wu_b    = (const float*)d_in[5];
    const float* wv_w    = (const float*)d_in[6];
    const float* wv_b    = (const float*)d_in[7];
    const float* wi_w    = (const float*)d_in[8];
    const float* wi_b    = (const float*)d_in[9];
    const float* ln1_w   = (const float*)d_in[10];
    const float* ln1_b   = (const float*)d_in[11];
    const float* pred_w  = (const float*)d_in[12];
    const float* pred_b  = (const float*)d_in[13];
    float* out = (float*)d_out;

    const int KSPLIT = 2;   // projection GEMM k-split
    const int KSPL   = 6;   // pair GEMM k-split (NIT=2)
    const int KSPP   = 12;  // pred GEMM k-split (NIT=1)
    const int NCH    = 64;  // pool chunks (RPC=8)
    const int RPC    = S / NCH;   // 8
    const int CVTY   = 27;  // cvt blocks per batch-column

    float* ws = (float*)d_ws;
    ushort_t* pooled_bf = (ushort_t*)ws;                            // M_TOT*D
    ushort_t* wbf = (ushort_t*)(ws + (size_t)M_TOT*D/2);            // 4*DD + R*D
    size_t wbf_fl = ((size_t)4*DD + (size_t)R*D + 1) / 2;
    float* p_part    = ws + (size_t)M_TOT*D/2 + wbf_fl;             // KSPLIT*M_TOT*D
    ushort_t* s_bf   = (ushort_t*)(p_part + (size_t)KSPLIT*M_TOT*D);// B*D
    float* pair_part = (float*)(s_bf + (size_t)B*D);                // KSPL*B*D
    float* chunkmax  = pair_part + (size_t)KSPL*B*D;                // B*NCH*D
    (void)ws_size; (void)in_sizes; (void)n_in; (void)out_size;

    k_pool1<RPC, NCH, CVTY><<<dim3(B, NCH + CVTY), 192, 0, stream>>>(
        emb, wu_w, wv_w, wi_w, ln1_w, pred_w, chunkmax, wbf);
    k_pool2<RPC, NCH><<<M_TOT, 192, 0, stream>>>(
        chunkmax, emb, h_span, t_span, b_spans, pooled_bf);
    k_gemm_bf<KSPLIT><<<dim3(D/64, M_TOT/64, KSPLIT), 256, 0, stream>>>(pooled_bf, wbf, p_part);
    k_att2<KSPLIT><<<B, 512, 0, stream>>>(p_part, wu_b, wv_b, wi_b, pred_b, s_bf, out);
    k_pairg_bf<KSPL><<<dim3(D/64, KSPL), 256, 0, stream>>>(s_bf, wbf + (size_t)3*DD, pair_part);
    k_predg_bf<KSPP, KSPL><<<dim3((R+63)/64, KSPP), 256, 0, stream>>>(
        pair_part, ln1_b, wbf + (size_t)4*DD, out);
}

// Round 15
// 53.482 us; speedup vs baseline: 1.1935x; 1.1935x over previous
//
#include <hip/hip_runtime.h>
#include <hip/hip_bf16.h>

// Problem constants
#define B 64
#define S 512
#define D 768
#define K 8
#define R 277
#define NSPAN 10     // h, t, 8 bridge spans per batch
#define M_TOT 640    // pooled rows: [u: 0..63][v: 64..127][bi: 128..639]
#define DD (D*D)

typedef unsigned short ushort_t;
typedef __attribute__((ext_vector_type(8))) short short8;
typedef __attribute__((ext_vector_type(4))) float f32x4;

__device__ __forceinline__ ushort_t f2bf(float f) {
    unsigned u = __float_as_uint(f);
    unsigned r = (u + 0x7FFFu + ((u >> 16) & 1u)) >> 16;   // RNE
    return (ushort_t)r;
}

// ---------------------------------------------------------------------------
// Pool phase 1 + weight cvt in one launch (R13 form + bf16 partials).
// Grid (B, NCH+CVTY), 192 thr.
//  y < NCH : streaming branchless span-max over chunk -> partial_bf (bf16;
//            exact: max commutes with monotone RNE rounding, and the final
//            pooled output is bf16 anyway). Early-exit on untouched chunks.
//  y >= NCH: fp32->bf16 conversion of {wu,wv,wi,ln1_w,pred_w} (independent)
// ---------------------------------------------------------------------------
template<int RPC, int NCH, int CVTY>
__global__ void k_pool1(const float* __restrict__ emb,
                        const int* __restrict__ h_span,
                        const int* __restrict__ t_span,
                        const int* __restrict__ b_spans,
                        const float* __restrict__ wu,
                        const float* __restrict__ wv,
                        const float* __restrict__ wi,
                        const float* __restrict__ ln1_w,
                        const float* __restrict__ pred_w,
                        ushort_t* __restrict__ partial_bf,
                        ushort_t* __restrict__ wbf) {
    int b = blockIdx.x, c = blockIdx.y;
    int t = threadIdx.x;

    if (c >= NCH) {
        // ---- cvt role: 8 elems/thread over 4*D*D + R*D elements ----
        int g = (b * CVTY + (c - NCH)) * 192 + t;
        size_t e0 = (size_t)g * 8;
        const size_t TOT = (size_t)4*DD + (size_t)R*D;
        if (e0 < TOT) {
            const float* src; size_t off;
            if      (e0 < (size_t)DD)   { src = wu;     off = e0; }
            else if (e0 < (size_t)2*DD) { src = wv;     off = e0 - DD; }
            else if (e0 < (size_t)3*DD) { src = wi;     off = e0 - (size_t)2*DD; }
            else if (e0 < (size_t)4*DD) { src = ln1_w;  off = e0 - (size_t)3*DD; }
            else                        { src = pred_w; off = e0 - (size_t)4*DD; }
            float4 f0 = *(const float4*)(src + off);
            float4 f1 = *(const float4*)(src + off + 4);
            short8 o;
            o[0] = (short)f2bf(f0.x); o[1] = (short)f2bf(f0.y);
            o[2] = (short)f2bf(f0.z); o[3] = (short)f2bf(f0.w);
            o[4] = (short)f2bf(f1.x); o[5] = (short)f2bf(f1.y);
            o[6] = (short)f2bf(f1.z); o[7] = (short)f2bf(f1.w);
            *(short8*)&wbf[e0] = o;
        }
        return;
    }

    int r0 = c * RPC;
    int s0[NSPAN], s1[NSPAN];
    s0[0] = h_span[b*2]; s1[0] = h_span[b*2+1];
    s0[1] = t_span[b*2]; s1[1] = t_span[b*2+1];
    #pragma unroll
    for (int k = 0; k < K; ++k) {
        s0[2+k] = b_spans[(b*K+k)*2];
        s1[2+k] = b_spans[(b*K+k)*2 + 1];
    }

    bool any = false;
    #pragma unroll
    for (int j = 0; j < NSPAN; ++j)
        any |= (s1[j] >= r0) && (s0[j] < r0 + RPC);
    if (!any) return;                      // uniform: untouched chunk

    float4 m[NSPAN];
    #pragma unroll
    for (int j = 0; j < NSPAN; ++j)
        m[j] = make_float4(-INFINITY, -INFINITY, -INFINITY, -INFINITY);

    const float4* e4 = (const float4*)(emb + (size_t)b * S * D) + (size_t)r0 * (D/4) + t;
    #pragma unroll
    for (int i = 0; i < RPC; ++i) {
        float4 v = e4[i * (D/4)];
        int s = r0 + i;
        #pragma unroll
        for (int j = 0; j < NSPAN; ++j) {
            bool in = (s >= s0[j]) && (s <= s1[j]);
            float vx = in ? v.x : -INFINITY;
            float vy = in ? v.y : -INFINITY;
            float vz = in ? v.z : -INFINITY;
            float vw = in ? v.w : -INFINITY;
            m[j].x = fmaxf(m[j].x, vx); m[j].y = fmaxf(m[j].y, vy);
            m[j].z = fmaxf(m[j].z, vz); m[j].w = fmaxf(m[j].w, vw);
        }
    }

    #pragma unroll
    for (int j = 0; j < NSPAN; ++j) {
        if (s1[j] >= r0 && s0[j] < r0 + RPC) {
            unsigned lo = (unsigned)f2bf(m[j].x) | ((unsigned)f2bf(m[j].y) << 16);
            unsigned hi = (unsigned)f2bf(m[j].z) | ((unsigned)f2bf(m[j].w) << 16);
            *(uint2*)&partial_bf[(((size_t)(b*NCH + c))*NSPAN + j) * D + t*4] =
                make_uint2(lo, hi);
        }
    }
}

// ---------------------------------------------------------------------------
// Pool phase 2: reduce intersecting bf16 chunk-partials; writes pooled BF16.
// bf16->fp32 unpack is exact (<<16 / mask); f2bf on bf16 values is identity.
// ---------------------------------------------------------------------------
template<int NCH>
__global__ void k_pool2(const ushort_t* __restrict__ partial_bf,
                        const int* __restrict__ h_span,
                        const int* __restrict__ t_span,
                        const int* __restrict__ b_spans,
                        ushort_t* __restrict__ pooled_bf, int rpc) {
    int task = blockIdx.x;
    int b = task / NSPAN, j = task % NSPAN;
    int s0, s1, row;
    if (j == 0)      { s0 = h_span[b*2]; s1 = h_span[b*2+1]; row = b; }
    else if (j == 1) { s0 = t_span[b*2]; s1 = t_span[b*2+1]; row = B + b; }
    else {
        int k = j - 2;
        s0 = b_spans[(b*K+k)*2]; s1 = b_spans[(b*K+k)*2 + 1];
        row = 2*B + b*K + k;
    }
    int c0 = s0 / rpc, c1 = s1 / rpc;
    int t = threadIdx.x;
    float4 m = make_float4(-INFINITY, -INFINITY, -INFINITY, -INFINITY);
    for (int c = c0; c <= c1; ++c) {
        uint2 v = *(const uint2*)&partial_bf[(((size_t)(b*NCH + c))*NSPAN + j) * D + t*4];
        float fx = __uint_as_float(v.x << 16);
        float fy = __uint_as_float(v.x & 0xFFFF0000u);
        float fz = __uint_as_float(v.y << 16);
        float fw = __uint_as_float(v.y & 0xFFFF0000u);
        m.x = fmaxf(m.x, fx); m.y = fmaxf(m.y, fy);
        m.z = fmaxf(m.z, fz); m.w = fmaxf(m.w, fw);
    }
    unsigned lo = (unsigned)f2bf(m.x) | ((unsigned)f2bf(m.y) << 16);
    unsigned hi = (unsigned)f2bf(m.z) | ((unsigned)f2bf(m.w) << 16);
    *(uint2*)&pooled_bf[(size_t)row * D + t*4] = make_uint2(lo, hi);
}

// ---------------------------------------------------------------------------
// Projection GEMM via bf16 MFMA 16x16x32 (R9-verified). grid (12,10,KSPLIT=2).
// ---------------------------------------------------------------------------
template<int KSPLIT>
__global__ __launch_bounds__(256)
void k_gemm_bf(const ushort_t* __restrict__ abf,
               const ushort_t* __restrict__ wbf,
               float* __restrict__ p_part) {
    __shared__ ushort_t Al[64][64];
    __shared__ ushort_t Bl[64][64];
    int e0 = blockIdx.x * 64;
    int m0 = blockIdx.y * 64;
    int dbase = blockIdx.z * (D / KSPLIT);
    const ushort_t* Wm = wbf + (size_t)((m0 < B) ? 0 : (m0 < 2*B) ? 1 : 2) * DD;

    int tid = threadIdx.x;
    int w = tid >> 6, l = tid & 63;
    int srow = tid >> 2;
    int sc   = tid & 3;

    const ushort_t* ga = abf + (size_t)(m0 + srow) * D + dbase;
    const ushort_t* gb = Wm  + (size_t)(e0 + srow) * D + dbase;
    int p0 = ((sc     ) ^ (srow & 7)) * 8;
    int p1 = ((sc + 4 ) ^ (srow & 7)) * 8;

    f32x4 acc[4] = {};
    const int NIT = (D / KSPLIT) / 64;
    short8 pa0 = *(const short8*)(ga + sc*8);
    short8 pa1 = *(const short8*)(ga + sc*8 + 32);
    short8 pb0 = *(const short8*)(gb + sc*8);
    short8 pb1 = *(const short8*)(gb + sc*8 + 32);

    for (int it = 0; it < NIT; ++it) {
        __syncthreads();
        *(short8*)&Al[srow][p0] = pa0;
        *(short8*)&Al[srow][p1] = pa1;
        *(short8*)&Bl[srow][p0] = pb0;
        *(short8*)&Bl[srow][p1] = pb1;
        __syncthreads();
        if (it + 1 < NIT) {
            ga += 64; gb += 64;
            pa0 = *(const short8*)(ga + sc*8);
            pa1 = *(const short8*)(ga + sc*8 + 32);
            pb0 = *(const short8*)(gb + sc*8);
            pb1 = *(const short8*)(gb + sc*8 + 32);
        }
        int g = l >> 4, x = l & 7;
        #pragma unroll
        for (int ks = 0; ks < 2; ++ks) {
            int chunk = ks*4 + g;
            short8 a = *(const short8*)&Al[w*16 + (l & 15)][(chunk ^ x) * 8];
            #pragma unroll
            for (int nt = 0; nt < 4; ++nt) {
                short8 bf = *(const short8*)&Bl[nt*16 + (l & 15)][(chunk ^ x) * 8];
                acc[nt] = __builtin_amdgcn_mfma_f32_16x16x32_bf16(a, bf, acc[nt], 0, 0, 0);
            }
        }
    }

    int r4 = (l >> 4) * 4, cc = l & 15;
    #pragma unroll
    for (int nt = 0; nt < 4; ++nt)
        #pragma unroll
        for (int r = 0; r < 4; ++r)
            p_part[((size_t)blockIdx.z * M_TOT + m0 + w*16 + r4 + r) * D + e0 + nt*16 + cc] = acc[nt][r];
}

// ---------------------------------------------------------------------------
// Attention: reduce partials+bias -> U,V,BI; dots; softmax; s -> BF16.
// Also initializes out[b][:] = pred_b.
// ---------------------------------------------------------------------------
template<int KSPLIT>
__global__ __launch_bounds__(512)
void k_att2(const float* __restrict__ p_part,
            const float* __restrict__ wu_b,
            const float* __restrict__ wv_b,
            const float* __restrict__ wi_b,
            const float* __restrict__ pred_b,
            ushort_t* __restrict__ s_bf,
            float* __restrict__ out) {
    __shared__ float U[D], V[D], BI[K][D];
    __shared__ float dots[K];
    int b = blockIdx.x, tid = threadIdx.x;

    for (int r = tid; r < R; r += 512) out[(size_t)b * R + r] = pred_b[r];

    for (int task = tid; task < NSPAN * (D/4); task += 512) {
        int j = task / (D/4), sl = task % (D/4);
        size_t row = (j == 0) ? (size_t)b : (j == 1) ? (size_t)(B + b)
                   : (size_t)(2*B + b*K + (j - 2));
        const float* bias = (j == 0) ? wu_b : (j == 1) ? wv_b : wi_b;
        float4 acc = *(const float4*)(bias + sl*4);
        #pragma unroll
        for (int ks = 0; ks < KSPLIT; ++ks) {
            float4 p = *(const float4*)(p_part + ((size_t)ks * M_TOT + row) * D + sl*4);
            acc.x += p.x; acc.y += p.y; acc.z += p.z; acc.w += p.w;
        }
        float* dst = (j == 0) ? U : (j == 1) ? V : BI[j-2];
        *(float4*)(dst + sl*4) = acc;
    }
    __syncthreads();

    int wave = tid >> 6, lane = tid & 63;
    {
        float part = 0.f;
        #pragma unroll
        for (int i = 0; i < D/64; ++i) {
            int d = i*64 + lane;
            part += U[d] * BI[wave][d];
        }
        #pragma unroll
        for (int off = 32; off > 0; off >>= 1) part += __shfl_xor(part, off);
        if (lane == 0) dots[wave] = part * 0.125f;   // 1/sqrt(D_K=64)
    }
    __syncthreads();

    float mx = -INFINITY;
    #pragma unroll
    for (int k = 0; k < K; ++k) mx = fmaxf(mx, dots[k]);
    float ex[K], sum = 0.f;
    #pragma unroll
    for (int k = 0; k < K; ++k) { ex[k] = expf(dots[k] - mx); sum += ex[k]; }
    float inv = 1.f / sum;
    for (int d = tid; d < D; d += 512) {
        float c = 0.f;
        #pragma unroll
        for (int k = 0; k < K; ++k) c += ex[k] * BI[k][d];
        s_bf[(size_t)b * D + d] = f2bf(U[d] + V[d] + c * inv);
    }
}

// ---------------------------------------------------------------------------
// pair GEMM via MFMA: A = s_bf [64][768], B = ln1_w bf16. grid (12, KSPL=6).
// ---------------------------------------------------------------------------
template<int KSPL>
__global__ __launch_bounds__(256)
void k_pairg_bf(const ushort_t* __restrict__ s_bf,
                const ushort_t* __restrict__ ln1_bf,
                float* __restrict__ pair_part) {
    __shared__ ushort_t Al[64][64];
    __shared__ ushort_t Bl[64][64];
    int e0 = blockIdx.x * 64;
    int dbase = blockIdx.y * (D / KSPL);

    int tid = threadIdx.x;
    int w = tid >> 6, l = tid & 63;
    int srow = tid >> 2;
    int sc   = tid & 3;

    const ushort_t* ga = s_bf   + (size_t)srow * D + dbase;
    const ushort_t* gb = ln1_bf + (size_t)(e0 + srow) * D + dbase;
    int p0 = ((sc     ) ^ (srow & 7)) * 8;
    int p1 = ((sc + 4 ) ^ (srow & 7)) * 8;

    f32x4 acc[4] = {};
    const int NIT = (D / KSPL) / 64;   // 2
    short8 pa0 = *(const short8*)(ga + sc*8);
    short8 pa1 = *(const short8*)(ga + sc*8 + 32);
    short8 pb0 = *(const short8*)(gb + sc*8);
    short8 pb1 = *(const short8*)(gb + sc*8 + 32);

    for (int it = 0; it < NIT; ++it) {
        __syncthreads();
        *(short8*)&Al[srow][p0] = pa0;
        *(short8*)&Al[srow][p1] = pa1;
        *(short8*)&Bl[srow][p0] = pb0;
        *(short8*)&Bl[srow][p1] = pb1;
        __syncthreads();
        if (it + 1 < NIT) {
            ga += 64; gb += 64;
            pa0 = *(const short8*)(ga + sc*8);
            pa1 = *(const short8*)(ga + sc*8 + 32);
            pb0 = *(const short8*)(gb + sc*8);
            pb1 = *(const short8*)(gb + sc*8 + 32);
        }
        int g = l >> 4, x = l & 7;
        #pragma unroll
        for (int ks = 0; ks < 2; ++ks) {
            int chunk = ks*4 + g;
            short8 a = *(const short8*)&Al[w*16 + (l & 15)][(chunk ^ x) * 8];
            #pragma unroll
            for (int nt = 0; nt < 4; ++nt) {
                short8 bf = *(const short8*)&Bl[nt*16 + (l & 15)][(chunk ^ x) * 8];
                acc[nt] = __builtin_amdgcn_mfma_f32_16x16x32_bf16(a, bf, acc[nt], 0, 0, 0);
            }
        }
    }

    int r4 = (l >> 4) * 4, cc = l & 15;
    #pragma unroll
    for (int nt = 0; nt < 4; ++nt)
        #pragma unroll
        for (int r = 0; r < 4; ++r)
            pair_part[((size_t)blockIdx.y * B + w*16 + r4 + r) * D + e0 + nt*16 + cc] = acc[nt][r];
}

// ---------------------------------------------------------------------------
// pred GEMM via MFMA: A = relu(sum_ks pair_part + ln1_b) built inline (bf16),
// B = pred_w bf16 (row-clamped). grid (5, KSPP=12), NIT=1, atomic epilogue.
// ---------------------------------------------------------------------------
template<int KSPP, int KSPL>
__global__ __launch_bounds__(256)
void k_predg_bf(const float* __restrict__ pair_part,
                const float* __restrict__ ln1_b,
                const ushort_t* __restrict__ pred_bf,
                float* __restrict__ out) {
    __shared__ ushort_t Al[64][64];
    __shared__ ushort_t Bl[64][64];
    int r0 = blockIdx.x * 64;
    int dbase = blockIdx.y * (D / KSPP);   // 64-elem K slice

    int tid = threadIdx.x;
    int w = tid >> 6, l = tid & 63;
    int srow = tid >> 2;
    int sc   = tid & 3;
    int p0 = ((sc     ) ^ (srow & 7)) * 8;
    int p1 = ((sc + 4 ) ^ (srow & 7)) * 8;

    auto build8 = [&](int off) -> short8 {   // off: elem offset in [0,64)
        float4 a0 = *(const float4*)(ln1_b + dbase + off);
        float4 a1 = *(const float4*)(ln1_b + dbase + off + 4);
        #pragma unroll
        for (int ks = 0; ks < KSPL; ++ks) {
            const float* p = pair_part + ((size_t)ks * B + srow) * D + dbase + off;
            float4 q0 = *(const float4*)p;
            float4 q1 = *(const float4*)(p + 4);
            a0.x += q0.x; a0.y += q0.y; a0.z += q0.z; a0.w += q0.w;
            a1.x += q1.x; a1.y += q1.y; a1.z += q1.z; a1.w += q1.w;
        }
        short8 o;
        o[0] = (short)f2bf(fmaxf(a0.x, 0.f)); o[1] = (short)f2bf(fmaxf(a0.y, 0.f));
        o[2] = (short)f2bf(fmaxf(a0.z, 0.f)); o[3] = (short)f2bf(fmaxf(a0.w, 0.f));
        o[4] = (short)f2bf(fmaxf(a1.x, 0.f)); o[5] = (short)f2bf(fmaxf(a1.y, 0.f));
        o[6] = (short)f2bf(fmaxf(a1.z, 0.f)); o[7] = (short)f2bf(fmaxf(a1.w, 0.f));
        return o;
    };

    short8 a0 = build8(sc*8);
    short8 a1 = build8(sc*8 + 32);
    int rw = r0 + srow; if (rw >= R) rw = R - 1;   // clamp (products discarded)
    const ushort_t* gb = pred_bf + (size_t)rw * D + dbase;
    short8 pb0 = *(const short8*)(gb + sc*8);
    short8 pb1 = *(const short8*)(gb + sc*8 + 32);

    *(short8*)&Al[srow][p0] = a0;
    *(short8*)&Al[srow][p1] = a1;
    *(short8*)&Bl[srow][p0] = pb0;
    *(short8*)&Bl[srow][p1] = pb1;
    __syncthreads();

    f32x4 acc[4] = {};
    int g = l >> 4, x = l & 7;
    #pragma unroll
    for (int ks = 0; ks < 2; ++ks) {
        int chunk = ks*4 + g;
        short8 a = *(const short8*)&Al[w*16 + (l & 15)][(chunk ^ x) * 8];
        #pragma unroll
        for (int nt = 0; nt < 4; ++nt) {
            short8 bf = *(const short8*)&Bl[nt*16 + (l & 15)][(chunk ^ x) * 8];
            acc[nt] = __builtin_amdgcn_mfma_f32_16x16x32_bf16(a, bf, acc[nt], 0, 0, 0);
        }
    }

    int r4 = (l >> 4) * 4, cc = l & 15;
    #pragma unroll
    for (int nt = 0; nt < 4; ++nt) {
        int rr = r0 + nt*16 + cc;
        if (rr < R) {
            #pragma unroll
            for (int r = 0; r < 4; ++r)
                atomicAdd(&out[(size_t)(w*16 + r4 + r) * R + rr], acc[nt][r]);
        }
    }
}

// ---------------------------------------------------------------------------
extern "C" void kernel_launch(void* const* d_in, const int* in_sizes, int n_in,
                              void* d_out, int out_size, void* d_ws, size_t ws_size,
                              hipStream_t stream) {
    const float* emb     = (const float*)d_in[0];
    const int*   h_span  = (const int*)  d_in[1];
    const int*   t_span  = (const int*)  d_in[2];
    const int*   b_spans = (const int*)  d_in[3];
    const float* wu_w    = (const float*)d_in[4];
    const float* wu_b    = (const float*)d_in[5];
    const float* wv_w    = (const float*)d_in[6];
    const float* wv_b    = (const float*)d_in[7];
    const float* wi_w    = (const float*)d_in[8];
    const float* wi_b    = (const float*)d_in[9];
    const float* ln1_w   = (const float*)d_in[10];
    const float* ln1_b   = (const float*)d_in[11];
    const float* pred_w  = (const float*)d_in[12];
    const float* pred_b  = (const float*)d_in[13];
    float* out = (float*)d_out;

    const int KSPLIT = 2;   // projection GEMM k-split
    const int KSPL   = 6;   // pair GEMM k-split (NIT=2)
    const int KSPP   = 12;  // pred GEMM k-split (NIT=1)
    const int NCH    = 32;  // pool chunks (RPC=16)
    const int RPC    = S / NCH;
    const int CVTY   = 27;  // cvt blocks per batch-column

    float* ws = (float*)d_ws;
    ushort_t* pooled_bf = (ushort_t*)ws;                            // M_TOT*D
    ushort_t* wbf = (ushort_t*)(ws + (size_t)M_TOT*D/2);            // 4*DD + R*D
    size_t wbf_fl = ((size_t)4*DD + (size_t)R*D + 1) / 2;
    float* p_part    = ws + (size_t)M_TOT*D/2 + wbf_fl;             // KSPLIT*M_TOT*D
    ushort_t* s_bf   = (ushort_t*)(p_part + (size_t)KSPLIT*M_TOT*D);// B*D
    float* pair_part = (float*)(s_bf + (size_t)B*D);                // KSPL*B*D
    ushort_t* partial_bf = (ushort_t*)(pair_part + (size_t)KSPL*B*D); // B*NCH*NSPAN*D bf16
    (void)ws_size; (void)in_sizes; (void)n_in; (void)out_size;

    k_pool1<RPC, NCH, CVTY><<<dim3(B, NCH + CVTY), 192, 0, stream>>>(
        emb, h_span, t_span, b_spans, wu_w, wv_w, wi_w, ln1_w, pred_w, partial_bf, wbf);
    k_pool2<NCH><<<M_TOT, 192, 0, stream>>>(
        partial_bf, h_span, t_span, b_spans, pooled_bf, RPC);
    k_gemm_bf<KSPLIT><<<dim3(D/64, M_TOT/64, KSPLIT), 256, 0, stream>>>(pooled_bf, wbf, p_part);
    k_att2<KSPLIT><<<B, 512, 0, stream>>>(p_part, wu_b, wv_b, wi_b, pred_b, s_bf, out);
    k_pairg_bf<KSPL><<<dim3(D/64, KSPL), 256, 0, stream>>>(s_bf, wbf + (size_t)3*DD, pair_part);
    k_predg_bf<KSPP, KSPL><<<dim3((R+63)/64, KSPP), 256, 0, stream>>>(
        pair_part, ln1_b, wbf + (size_t)4*DD, out);
}